// Round 5
// baseline (1157.026 us; speedup 1.0000x reference)
//
#include <hip/hip_runtime.h>

typedef short s16x8 __attribute__((ext_vector_type(8)));
typedef float f32x4 __attribute__((ext_vector_type(4)));

#define LDW 136    // padded LDS row stride in shorts (128 + 8)
#define BCAP 1536  // slab capacity per (relation,bin): mean fill 1024, ~16 sigma margin

__device__ __forceinline__ unsigned short f2bf(float x) {
    unsigned int u = __builtin_bit_cast(unsigned int, x);
    u = (u + 0x7fffu + ((u >> 16) & 1u)) >> 16;   // RNE
    return (unsigned short)u;
}
__device__ __forceinline__ float bf2f(unsigned int lo) {
    return __builtin_bit_cast(float, lo << 16);
}

// ---- out-degree histogram (src only) ----
__global__ __launch_bounds__(256) void degO_kernel(const int* __restrict__ src,
                                                   unsigned int* __restrict__ cntO,
                                                   int RE, int E, int N) {
    int idx = blockIdx.x * 256 + threadIdx.x;
    if (idx >= RE) return;
    int r = idx / E;
    atomicAdd(&cntO[(size_t)r * N + src[idx]], 1u);
}

__global__ __launch_bounds__(256) void norm_kernel(const unsigned int* __restrict__ cntO,
                                                   const unsigned int* __restrict__ cntI,
                                                   float* __restrict__ normO,
                                                   float* __restrict__ normI,
                                                   int RN) {
    int idx = blockIdx.x * 256 + threadIdx.x;
    if (idx < RN)        normO[idx]      = rsqrtf(fmaxf((float)cntO[idx], 1.0f));
    else if (idx < 2*RN) normI[idx - RN] = rsqrtf(fmaxf((float)cntI[idx - RN], 1.0f));
}

// ---- W fp32 -> bf16, transposed: WbfT[which][n][k] = bf16(W[which][k][n]) ----
__global__ __launch_bounds__(256) void wconv_kernel(const float* __restrict__ W1,
                                                    const float* __restrict__ W2,
                                                    unsigned short* __restrict__ WbfT,
                                                    int total) {
    int idx = blockIdx.x * 256 + threadIdx.x;
    if (idx >= total) return;
    int which = idx >> 14;
    int k = (idx >> 7) & 127;
    int n = idx & 127;
    int outi = (idx & ~16383) | (n << 7) | k;
    const float* W = (which < 3) ? (W1 + (size_t)which * 16384)
                                 : (W2 + (size_t)(which - 3) * 16384);
    WbfT[outi] = f2bf(W[k * 128 + n]);
}

// ---- coarse binned scatter: slab[r][dst>>7] gets packed (src | dstLocal<<17) ----
__global__ __launch_bounds__(256) void bin_scatter(const int* __restrict__ src,
                                                   const int* __restrict__ dst,
                                                   unsigned int* __restrict__ binCursor,
                                                   unsigned int* __restrict__ binned,
                                                   int RE, int E, int NB) {
    int idx = blockIdx.x * 256 + threadIdx.x;
    if (idx >= RE) return;
    int r = idx / E;
    int d = dst[idx];
    int gbin = r * NB + (d >> 7);
    unsigned int pos = atomicAdd(&binCursor[gbin], 1u);
    if (pos < BCAP)
        binned[(size_t)gbin * BCAP + pos] =
            (unsigned int)src[idx] | ((unsigned int)(d & 127) << 17);
}

// ---- exclusive scan over M bin counts -> compact CSR slab bases (1 block) ----
__global__ __launch_bounds__(256) void bin_scan(const unsigned int* __restrict__ binCursor,
                                                int* __restrict__ binStart, int M) {
    int t = threadIdx.x;
    int K = (M + 255) / 256;
    int lo = t * K;
    int s = 0;
    for (int j = 0; j < K; ++j) {
        int i = lo + j;
        if (i < M) s += (int)min(binCursor[i], (unsigned)BCAP);
    }
    int lane = t & 63, w = t >> 6;
    int x = s;
#pragma unroll
    for (int d2 = 1; d2 < 64; d2 <<= 1) { int y = __shfl_up(x, d2, 64); if (lane >= d2) x += y; }
    __shared__ int ws[4];
    if (lane == 63) ws[w] = x;
    __syncthreads();
    int wb = 0;
    for (int k = 0; k < 4; ++k) if (k < w) wb += ws[k];
    int pre = wb + x - s;
    for (int j = 0; j < K; ++j) {
        int i = lo + j;
        if (i < M) {
            binStart[i] = pre;
            pre += (int)min(binCursor[i], (unsigned)BCAP);
        }
    }
}

// ---- fine sort within one slab: per-node counts, CSR offs, compact bucket ----
__global__ __launch_bounds__(256) void fine_sort(const unsigned int* __restrict__ binned,
                                                 const unsigned int* __restrict__ binCursor,
                                                 const int* __restrict__ binStart,
                                                 int* __restrict__ bucket,
                                                 unsigned int* __restrict__ cntI,
                                                 int* __restrict__ offs,
                                                 int N, int NB) {
    __shared__ unsigned int ed[BCAP];
    __shared__ unsigned int hist[128];
    __shared__ int exc[128];
    __shared__ unsigned int cur[128];
    __shared__ int w0tot;
    int t = threadIdx.x;
    int gbin = blockIdx.x;
    int r = gbin / NB, b = gbin % NB;
    int cnt = (int)min(binCursor[gbin], (unsigned)BCAP);
    int base = binStart[gbin];
    if (t < 128) { hist[t] = 0u; cur[t] = 0u; }
    __syncthreads();
    const unsigned int* slab = binned + (size_t)gbin * BCAP;
    for (int i = t; i < cnt; i += 256) {
        unsigned int u = slab[i];
        ed[i] = u;
        atomicAdd(&hist[u >> 17], 1u);
    }
    __syncthreads();
    // exclusive scan of hist[0..127] (first two waves carry the data)
    int v = 0;
    if (t < 128) v = (int)hist[t];
    int x = v;
    int lane = t & 63;
#pragma unroll
    for (int d2 = 1; d2 < 64; d2 <<= 1) { int y = __shfl_up(x, d2, 64); if (lane >= d2) x += y; }
    if (t == 63) w0tot = x;
    __syncthreads();
    if (t >= 64 && t < 128) x += w0tot;
    if (t < 128) {
        int e = x - v;
        exc[t] = e;
        int node = b * 128 + t;
        if (node < N) {
            cntI[(size_t)r * N + node] = (unsigned int)v;
            offs[(size_t)r * N + node] = base + e;   // absolute into bucket[R*E]
        }
    }
    __syncthreads();
    for (int i = t; i < cnt; i += 256) {
        unsigned int u = ed[i];
        int nl = (int)(u >> 17);
        int rank = (int)atomicAdd(&cur[nl], 1u);
        bucket[base + exc[nl] + rank] = (int)(u & 0x1FFFFu);
    }
}

// ---- fused 3-relation GEMM: T[r][n][c] = bf16( normO[r][n] * (X @ W_r)[n][c] ) ----
template <bool BF16IN>
__global__ __launch_bounds__(256) void gemm3(const void* __restrict__ Xp,
                                             const unsigned short* __restrict__ WbfT, // [3][128][128] n-major
                                             const float* __restrict__ normO,        // [3][N]
                                             unsigned short* __restrict__ T,         // [3][N][128]
                                             int nrows) {
    __shared__ unsigned short Xl[64 * LDW];
    __shared__ unsigned short Wl[128 * LDW];
    int tid = threadIdx.x;
    int row0 = blockIdx.x * 64;

#pragma unroll
    for (int j = 0; j < 8; ++j) {
        int f4 = tid + j * 256;
        int row = f4 >> 5;
        int k0 = (f4 & 31) * 4;
        int gr = row0 + row;
        if (BF16IN) {
            uint2 v = make_uint2(0u, 0u);
            if (gr < nrows) v = ((const uint2*)Xp)[(size_t)gr * 32 + (f4 & 31)];
            *(uint2*)(&Xl[row * LDW + k0]) = v;
        } else {
            float4 v = make_float4(0.f, 0.f, 0.f, 0.f);
            if (gr < nrows) v = ((const float4*)Xp)[(size_t)gr * 32 + (f4 & 31)];
            unsigned long long pk = (unsigned long long)f2bf(v.x)
                                  | ((unsigned long long)f2bf(v.y) << 16)
                                  | ((unsigned long long)f2bf(v.z) << 32)
                                  | ((unsigned long long)f2bf(v.w) << 48);
            *(unsigned long long*)(&Xl[row * LDW + k0]) = pk;
        }
    }
#pragma unroll
    for (int j = 0; j < 8; ++j) {
        int i = tid + j * 256;            // 2048 uint4 chunks = 128*128 shorts
        int row = i >> 4, c0 = (i & 15) * 8;
        *(uint4*)(Wl + row * LDW + c0) = ((const uint4*)WbfT)[i];
    }
    __syncthreads();

    int wave = tid >> 6, lane = tid & 63;
    int laneM = lane & 15, quad = lane >> 4;
    int m0 = wave * 16;

    s16x8 afr[4];
#pragma unroll
    for (int ks = 0; ks < 4; ++ks)
        afr[ks] = *(const s16x8*)(Xl + (m0 + laneM) * LDW + ks * 32 + quad * 8);

    for (int r = 0; r < 3; ++r) {
        f32x4 acc[8];
#pragma unroll
        for (int ct = 0; ct < 8; ++ct) acc[ct] = (f32x4){0.f, 0.f, 0.f, 0.f};
#pragma unroll
        for (int ks = 0; ks < 4; ++ks) {
            int k = ks * 32 + quad * 8;
#pragma unroll
            for (int ct = 0; ct < 8; ++ct) {
                s16x8 b = *(const s16x8*)(Wl + (ct * 16 + laneM) * LDW + k);
                acc[ct] = __builtin_amdgcn_mfma_f32_16x16x32_bf16(afr[ks], b, acc[ct], 0, 0, 0);
            }
        }
        unsigned short* Tr = T + (size_t)r * nrows * 128;
        const float* nrm = normO + (size_t)r * nrows;
#pragma unroll
        for (int i = 0; i < 4; ++i) {
            int gr = row0 + m0 + quad * 4 + i;
            if (gr < nrows) {
                float sc = nrm[gr];
#pragma unroll
                for (int ct = 0; ct < 8; ++ct)
                    Tr[(size_t)gr * 128 + ct * 16 + laneM] = f2bf(acc[ct][i] * sc);
            }
        }
        if (r < 2) {
            __syncthreads();
#pragma unroll
            for (int j = 0; j < 8; ++j) {
                int i = tid + j * 256;
                int row = i >> 4, c0 = (i & 15) * 8;
                *(uint4*)(Wl + row * LDW + c0) =
                    ((const uint4*)(WbfT + (size_t)(r + 1) * 16384))[i];
            }
            __syncthreads();
        }
    }
}

// ---- gather: one wave per dst node, fused over R relations + bias (+relu) ----
template <bool RELU, bool BF16OUT>
__global__ __launch_bounds__(256) void gather_kernel(const unsigned short* __restrict__ T, // [R][N][128]
                                                     const int* __restrict__ bucket,       // [R*E] compact
                                                     const int* __restrict__ offs,         // [R][N] absolute
                                                     const unsigned int* __restrict__ cnt, // [R][N]
                                                     const float* __restrict__ normI,      // [R][N]
                                                     const float* __restrict__ bias,       // [R][128]
                                                     void* __restrict__ out,
                                                     int N, int E) {
    int n = blockIdx.x * 4 + (threadIdx.x >> 6);
    if (n >= N) return;
    int lane = threadIdx.x & 63;
    float a0 = 0.f, a1 = 0.f;
    const float2* bv = (const float2*)bias;
#pragma unroll
    for (int r = 0; r < 3; ++r) {
        float p0 = 0.f, p1 = 0.f;
        int start = offs[(size_t)r * N + n];
        int c = (int)cnt[(size_t)r * N + n];
        const unsigned int* Tr = (const unsigned int*)(T + (size_t)r * N * 128);
        const int* bk = bucket + start;       // offs is absolute now
        for (int base = 0; base < c; base += 64) {
            int m = min(64, c - base);
            int id = (lane < m) ? bk[base + lane] : 0;
            for (int j = 0; j < m; ++j) {
                int s2 = __shfl(id, j, 64);
                unsigned int v = Tr[(size_t)s2 * 64 + lane];
                p0 += bf2f(v & 0xffffu);
                p1 += bf2f(v >> 16);
            }
        }
        float nd = normI[(size_t)r * N + n];
        float2 bb = bv[r * 64 + lane];
        a0 += p0 * nd + bb.x;
        a1 += p1 * nd + bb.y;
    }
    if (RELU) { a0 = fmaxf(a0, 0.f); a1 = fmaxf(a1, 0.f); }
    if (BF16OUT) {
        unsigned int pk = (unsigned int)f2bf(a0) | ((unsigned int)f2bf(a1) << 16);
        ((unsigned int*)out)[(size_t)n * 64 + lane] = pk;
    } else {
        ((float2*)((float*)out + (size_t)n * 128))[lane] = make_float2(a0, a1);
    }
}

extern "C" void kernel_launch(void* const* d_in, const int* in_sizes, int n_in,
                              void* d_out, int out_size, void* d_ws, size_t ws_size,
                              hipStream_t stream) {
    const float* x  = (const float*)d_in[0];
    const int* src  = (const int*)d_in[1];
    const int* dst  = (const int*)d_in[2];
    const float* W1 = (const float*)d_in[3];
    const float* b1 = (const float*)d_in[4];
    const float* W2 = (const float*)d_in[5];
    const float* b2 = (const float*)d_in[6];
    float* out = (float*)d_out;

    const int R = 3;
    int N = in_sizes[0] / 128;
    int E = in_sizes[1] / R;
    int RN = R * N, RE = R * E;
    int NB = (N + 127) >> 7;       // 128-node bins
    int M  = R * NB;

    size_t h1b = (size_t)N * 128 * 2;          // bf16 hidden
    size_t Tb  = (size_t)R * N * 128 * 2;      // bf16 messages (binned slabs alias its front)
    size_t ib  = (size_t)RN * 4;               // one [R][N] int/float array
    size_t bb  = (size_t)RE * 4;               // compact bucket
    size_t wb  = (size_t)2 * R * 16384 * 2;    // bf16 transposed weights
    size_t mb  = (size_t)M * 4;                // binCursor / binStart
    size_t need_bin = (size_t)M * BCAP * 4;
    if (ws_size < h1b + Tb + 5 * ib + bb + wb + 2 * mb || Tb < need_bin) return;

    char* w = (char*)d_ws;
    unsigned short* h1   = (unsigned short*)w;            w += h1b;
    unsigned short* T    = (unsigned short*)w;            w += Tb;
    unsigned int* binned = (unsigned int*)T;              // alias: dead before gemm3 writes T
    unsigned int* cntO   = (unsigned int*)w;              w += ib;
    unsigned int* cntI   = (unsigned int*)w;              w += ib;
    float* normO         = (float*)w;                     w += ib;
    float* normI         = (float*)w;                     w += ib;
    int* offs            = (int*)w;                       w += ib;
    int* bucket          = (int*)w;                       w += bb;
    unsigned short* WbfT = (unsigned short*)w;            w += wb;
    unsigned int* binCursor = (unsigned int*)w;           w += mb;
    int* binStart        = (int*)w;

    hipMemsetAsync(cntO, 0, ib, stream);
    hipMemsetAsync(binCursor, 0, mb, stream);

    wconv_kernel<<<(2 * R * 16384 + 255) / 256, 256, 0, stream>>>(W1, W2, WbfT, 2 * R * 16384);
    degO_kernel<<<(RE + 255) / 256, 256, 0, stream>>>(src, cntO, RE, E, N);
    bin_scatter<<<(RE + 255) / 256, 256, 0, stream>>>(src, dst, binCursor, binned, RE, E, NB);
    bin_scan<<<1, 256, 0, stream>>>(binCursor, binStart, M);
    fine_sort<<<M, 256, 0, stream>>>(binned, binCursor, binStart, bucket, cntI, offs, N, NB);
    norm_kernel<<<(2 * RN + 255) / 256, 256, 0, stream>>>(cntO, cntI, normO, normI, RN);

    int gb = (N + 63) / 64;
    int ngb = (N + 3) / 4;

    // layer 1
    gemm3<false><<<gb, 256, 0, stream>>>(x, WbfT, normO, T, N);
    gather_kernel<true, true><<<ngb, 256, 0, stream>>>(T, bucket, offs, cntI, normI, b1, h1, N, E);

    // layer 2
    gemm3<true><<<gb, 256, 0, stream>>>(h1, WbfT + (size_t)3 * 16384, normO, T, N);
    gather_kernel<false, false><<<ngb, 256, 0, stream>>>(T, bucket, offs, cntI, normI, b2, out, N, E);
}

// Round 7
// 908.040 us; speedup vs baseline: 1.2742x; 1.2742x over previous
//
#include <hip/hip_runtime.h>

typedef short s16x8 __attribute__((ext_vector_type(8)));
typedef float f32x4 __attribute__((ext_vector_type(4)));

#define LDW 136   // padded LDS row stride in shorts (128 + 8)
#define CH 4096   // scan chunk size

__device__ __forceinline__ unsigned short f2bf(float x) {
    unsigned int u = __builtin_bit_cast(unsigned int, x);
    u = (u + 0x7fffu + ((u >> 16) & 1u)) >> 16;   // RNE
    return (unsigned short)u;
}
__device__ __forceinline__ float bf2f(unsigned int lo) {
    return __builtin_bit_cast(float, lo << 16);
}

// ---- degree histograms (low-contention: 300k counters, mean 8 hits) ----
__global__ __launch_bounds__(256) void deg_kernel(const int* __restrict__ src,
                                                  const int* __restrict__ dst,
                                                  unsigned int* __restrict__ cntO,
                                                  unsigned int* __restrict__ cntI,
                                                  int RE, int E, int N) {
    int idx = blockIdx.x * 256 + threadIdx.x;
    if (idx >= RE) return;
    int r = idx / E;
    atomicAdd(&cntO[(size_t)r * N + src[idx]], 1u);
    atomicAdd(&cntI[(size_t)r * N + dst[idx]], 1u);
}

__global__ __launch_bounds__(256) void norm_kernel(const unsigned int* __restrict__ cntO,
                                                   const unsigned int* __restrict__ cntI,
                                                   float* __restrict__ normO,
                                                   float* __restrict__ normI,
                                                   int RN) {
    int idx = blockIdx.x * 256 + threadIdx.x;
    if (idx < RN)        normO[idx]      = rsqrtf(fmaxf((float)cntO[idx], 1.0f));
    else if (idx < 2*RN) normI[idx - RN] = rsqrtf(fmaxf((float)cntI[idx - RN], 1.0f));
}

// ---- W fp32 -> bf16, transposed: WbfT[which][n][k] = bf16(W[which][k][n]) ----
__global__ __launch_bounds__(256) void wconv_kernel(const float* __restrict__ W1,
                                                    const float* __restrict__ W2,
                                                    unsigned short* __restrict__ WbfT,
                                                    int total) {
    int idx = blockIdx.x * 256 + threadIdx.x;
    if (idx >= total) return;
    int which = idx >> 14;
    int k = (idx >> 7) & 127;
    int n = idx & 127;
    int outi = (idx & ~16383) | (n << 7) | k;
    const float* W = (which < 3) ? (W1 + (size_t)which * 16384)
                                 : (W2 + (size_t)(which - 3) * 16384);
    WbfT[outi] = f2bf(W[k * 128 + n]);
}

// ---- two-level scan of cntI per relation ----
__global__ __launch_bounds__(256) void scanA(const unsigned int* __restrict__ cnt,
                                             int* __restrict__ csum, int N, int NC) {
    int r = blockIdx.x / NC, c = blockIdx.x % NC;
    const unsigned int* p = cnt + (size_t)r * N + c * CH;
    int lim = N - c * CH; if (lim > CH) lim = CH;
    int t = threadIdx.x;
    int s = 0;
    for (int i = t; i < lim; i += 256) s += (int)p[i];
#pragma unroll
    for (int d = 32; d; d >>= 1) s += __shfl_down(s, d, 64);
    __shared__ int ws[4];
    if ((t & 63) == 0) ws[t >> 6] = s;
    __syncthreads();
    if (t == 0) csum[blockIdx.x] = ws[0] + ws[1] + ws[2] + ws[3];
}

__global__ __launch_bounds__(256) void scanB(int* __restrict__ csum, int RC, int NC) {
    __shared__ int s[1024];
    int t = threadIdx.x;
    for (int i = t; i < RC; i += 256) s[i] = csum[i];
    __syncthreads();
    if (t < RC / NC) {
        int base = 0;
        for (int c = 0; c < NC; ++c) {
            int v = s[t * NC + c];
            s[t * NC + c] = base;
            base += v;
        }
    }
    __syncthreads();
    for (int i = t; i < RC; i += 256) csum[i] = s[i];
}

__global__ __launch_bounds__(256) void scanC(const unsigned int* __restrict__ cnt,
                                             const int* __restrict__ csum,
                                             int* __restrict__ offs,
                                             int* __restrict__ cursor,
                                             int N, int NC) {
    int r = blockIdx.x / NC, c = blockIdx.x % NC;
    int gbase = c * CH;
    const unsigned int* p = cnt + (size_t)r * N + gbase;
    int lim = N - gbase;
    int t = threadIdx.x;
    int i0 = t * 16;
    unsigned int v[16];
    if (i0 + 16 <= lim) {
        const uint4* q = (const uint4*)(p + i0);
        uint4 a0 = q[0], a1 = q[1], a2 = q[2], a3 = q[3];
        v[0]=a0.x; v[1]=a0.y; v[2]=a0.z; v[3]=a0.w;
        v[4]=a1.x; v[5]=a1.y; v[6]=a1.z; v[7]=a1.w;
        v[8]=a2.x; v[9]=a2.y; v[10]=a2.z; v[11]=a2.w;
        v[12]=a3.x; v[13]=a3.y; v[14]=a3.z; v[15]=a3.w;
    } else {
#pragma unroll
        for (int j = 0; j < 16; ++j) v[j] = (i0 + j < lim) ? p[i0 + j] : 0u;
    }
    int tot = 0;
#pragma unroll
    for (int j = 0; j < 16; ++j) tot += (int)v[j];
    int lane = t & 63, w = t >> 6;
    int x = tot;
#pragma unroll
    for (int d = 1; d < 64; d <<= 1) { int y = __shfl_up(x, d, 64); if (lane >= d) x += y; }
    __shared__ int ws[4];
    if (lane == 63) ws[w] = x;
    __syncthreads();
    int wbase = 0;
    for (int k = 0; k < 4; ++k) if (k < w) wbase += ws[k];
    int pre = csum[blockIdx.x] + wbase + (x - tot);
    int* o  = offs   + (size_t)r * N + gbase;
    int* cu = cursor + (size_t)r * N + gbase;
#pragma unroll
    for (int j = 0; j < 16; ++j) {
        int i = i0 + j;
        if (i < lim) { o[i] = pre; cu[i] = pre; }
        pre += (int)v[j];
    }
}

// ---- FUSED: blocks [0,gb) = layer-1 gemm3 (fp32 input); blocks [gb,..) = bucket scatter ----
// Independent work co-scheduled in one dispatch: gemm3 is MFMA/LDS-bound, bucket is
// memory-side atomic-bound — different pipes, ~max() not sum() (m114).
__global__ __launch_bounds__(256) void gemm3_bucket(const float* __restrict__ Xp,
                                                    const unsigned short* __restrict__ WbfT,
                                                    const float* __restrict__ normO,
                                                    unsigned short* __restrict__ T,
                                                    int nrows, int gb,
                                                    const int* __restrict__ src,
                                                    const int* __restrict__ dst,
                                                    int* __restrict__ cursor,
                                                    int* __restrict__ bucket,
                                                    int RE, int E, int N) {
    __shared__ unsigned short Xl[64 * LDW];
    __shared__ unsigned short Wl[128 * LDW];
    int tid = threadIdx.x;

    if ((int)blockIdx.x >= gb) {
        // ---- bucket branch: counting-sort scatter (R4-proven low-contention form) ----
        int idx = ((int)blockIdx.x - gb) * 256 + tid;
        if (idx >= RE) return;
        int r = idx / E;
        int d = dst[idx];
        int pos = atomicAdd(&cursor[(size_t)r * N + d], 1);
        bucket[(size_t)r * E + pos] = src[idx];
        return;
    }

    // ---- gemm3 layer-1 branch ----
    int row0 = blockIdx.x * 64;
#pragma unroll
    for (int j = 0; j < 8; ++j) {
        int f4 = tid + j * 256;
        int row = f4 >> 5;
        int k0 = (f4 & 31) * 4;
        int gr = row0 + row;
        float4 v = make_float4(0.f, 0.f, 0.f, 0.f);
        if (gr < nrows) v = ((const float4*)Xp)[(size_t)gr * 32 + (f4 & 31)];
        unsigned long long pk = (unsigned long long)f2bf(v.x)
                              | ((unsigned long long)f2bf(v.y) << 16)
                              | ((unsigned long long)f2bf(v.z) << 32)
                              | ((unsigned long long)f2bf(v.w) << 48);
        *(unsigned long long*)(&Xl[row * LDW + k0]) = pk;
    }
#pragma unroll
    for (int j = 0; j < 8; ++j) {
        int i = tid + j * 256;            // 2048 uint4 chunks = 128*128 shorts
        int row = i >> 4, c0 = (i & 15) * 8;
        *(uint4*)(Wl + row * LDW + c0) = ((const uint4*)WbfT)[i];
    }
    __syncthreads();

    int wave = tid >> 6, lane = tid & 63;
    int laneM = lane & 15, quad = lane >> 4;
    int m0 = wave * 16;

    s16x8 afr[4];
#pragma unroll
    for (int ks = 0; ks < 4; ++ks)
        afr[ks] = *(const s16x8*)(Xl + (m0 + laneM) * LDW + ks * 32 + quad * 8);

    for (int r = 0; r < 3; ++r) {
        f32x4 acc[8];
#pragma unroll
        for (int ct = 0; ct < 8; ++ct) acc[ct] = (f32x4){0.f, 0.f, 0.f, 0.f};
#pragma unroll
        for (int ks = 0; ks < 4; ++ks) {
            int k = ks * 32 + quad * 8;
#pragma unroll
            for (int ct = 0; ct < 8; ++ct) {
                s16x8 b = *(const s16x8*)(Wl + (ct * 16 + laneM) * LDW + k);
                acc[ct] = __builtin_amdgcn_mfma_f32_16x16x32_bf16(afr[ks], b, acc[ct], 0, 0, 0);
            }
        }
        unsigned short* Tr = T + (size_t)r * nrows * 128;
        const float* nrm = normO + (size_t)r * nrows;
#pragma unroll
        for (int i = 0; i < 4; ++i) {
            int gr = row0 + m0 + quad * 4 + i;
            if (gr < nrows) {
                float sc = nrm[gr];
#pragma unroll
                for (int ct = 0; ct < 8; ++ct)
                    Tr[(size_t)gr * 128 + ct * 16 + laneM] = f2bf(acc[ct][i] * sc);
            }
        }
        if (r < 2) {
            __syncthreads();
#pragma unroll
            for (int j = 0; j < 8; ++j) {
                int i = tid + j * 256;
                int row = i >> 4, c0 = (i & 15) * 8;
                *(uint4*)(Wl + row * LDW + c0) =
                    ((const uint4*)(WbfT + (size_t)(r + 1) * 16384))[i];
            }
            __syncthreads();
        }
    }
}

// ---- layer-2 gemm (bf16 input) ----
__global__ __launch_bounds__(256) void gemm3_bf16(const unsigned short* __restrict__ Xp,
                                                  const unsigned short* __restrict__ WbfT,
                                                  const float* __restrict__ normO,
                                                  unsigned short* __restrict__ T,
                                                  int nrows) {
    __shared__ unsigned short Xl[64 * LDW];
    __shared__ unsigned short Wl[128 * LDW];
    int tid = threadIdx.x;
    int row0 = blockIdx.x * 64;

#pragma unroll
    for (int j = 0; j < 8; ++j) {
        int f4 = tid + j * 256;
        int row = f4 >> 5;
        int k0 = (f4 & 31) * 4;
        int gr = row0 + row;
        uint2 v = make_uint2(0u, 0u);
        if (gr < nrows) v = ((const uint2*)Xp)[(size_t)gr * 32 + (f4 & 31)];
        *(uint2*)(&Xl[row * LDW + k0]) = v;
    }
#pragma unroll
    for (int j = 0; j < 8; ++j) {
        int i = tid + j * 256;
        int row = i >> 4, c0 = (i & 15) * 8;
        *(uint4*)(Wl + row * LDW + c0) = ((const uint4*)WbfT)[i];
    }
    __syncthreads();

    int wave = tid >> 6, lane = tid & 63;
    int laneM = lane & 15, quad = lane >> 4;
    int m0 = wave * 16;

    s16x8 afr[4];
#pragma unroll
    for (int ks = 0; ks < 4; ++ks)
        afr[ks] = *(const s16x8*)(Xl + (m0 + laneM) * LDW + ks * 32 + quad * 8);

    for (int r = 0; r < 3; ++r) {
        f32x4 acc[8];
#pragma unroll
        for (int ct = 0; ct < 8; ++ct) acc[ct] = (f32x4){0.f, 0.f, 0.f, 0.f};
#pragma unroll
        for (int ks = 0; ks < 4; ++ks) {
            int k = ks * 32 + quad * 8;
#pragma unroll
            for (int ct = 0; ct < 8; ++ct) {
                s16x8 b = *(const s16x8*)(Wl + (ct * 16 + laneM) * LDW + k);
                acc[ct] = __builtin_amdgcn_mfma_f32_16x16x32_bf16(afr[ks], b, acc[ct], 0, 0, 0);
            }
        }
        unsigned short* Tr = T + (size_t)r * nrows * 128;
        const float* nrm = normO + (size_t)r * nrows;
#pragma unroll
        for (int i = 0; i < 4; ++i) {
            int gr = row0 + m0 + quad * 4 + i;
            if (gr < nrows) {
                float sc = nrm[gr];
#pragma unroll
                for (int ct = 0; ct < 8; ++ct)
                    Tr[(size_t)gr * 128 + ct * 16 + laneM] = f2bf(acc[ct][i] * sc);
            }
        }
        if (r < 2) {
            __syncthreads();
#pragma unroll
            for (int j = 0; j < 8; ++j) {
                int i = tid + j * 256;
                int row = i >> 4, c0 = (i & 15) * 8;
                *(uint4*)(Wl + row * LDW + c0) =
                    ((const uint4*)(WbfT + (size_t)(r + 1) * 16384))[i];
            }
            __syncthreads();
        }
    }
}

// ---- gather: one wave per dst node, fused over R relations + bias (+relu) ----
template <bool RELU, bool BF16OUT>
__global__ __launch_bounds__(256) void gather_kernel(const unsigned short* __restrict__ T, // [R][N][128]
                                                     const int* __restrict__ bucket,       // [R][E]
                                                     const int* __restrict__ offs,         // [R][N] rel-relative
                                                     const unsigned int* __restrict__ cnt, // [R][N]
                                                     const float* __restrict__ normI,      // [R][N]
                                                     const float* __restrict__ bias,       // [R][128]
                                                     void* __restrict__ out,
                                                     int N, int E) {
    int n = blockIdx.x * 4 + (threadIdx.x >> 6);
    if (n >= N) return;
    int lane = threadIdx.x & 63;
    float a0 = 0.f, a1 = 0.f;
    const float2* bv = (const float2*)bias;
#pragma unroll
    for (int r = 0; r < 3; ++r) {
        float p0 = 0.f, p1 = 0.f;
        int start = offs[(size_t)r * N + n];
        int c = (int)cnt[(size_t)r * N + n];
        const unsigned int* Tr = (const unsigned int*)(T + (size_t)r * N * 128);
        const int* bk = bucket + (size_t)r * E + start;
        for (int base = 0; base < c; base += 64) {
            int m = min(64, c - base);
            int id = (lane < m) ? bk[base + lane] : 0;
            for (int j = 0; j < m; ++j) {
                int s2 = __shfl(id, j, 64);
                unsigned int v = Tr[(size_t)s2 * 64 + lane];
                p0 += bf2f(v & 0xffffu);
                p1 += bf2f(v >> 16);
            }
        }
        float nd = normI[(size_t)r * N + n];
        float2 bb = bv[r * 64 + lane];
        a0 += p0 * nd + bb.x;
        a1 += p1 * nd + bb.y;
    }
    if (RELU) { a0 = fmaxf(a0, 0.f); a1 = fmaxf(a1, 0.f); }
    if (BF16OUT) {
        unsigned int pk = (unsigned int)f2bf(a0) | ((unsigned int)f2bf(a1) << 16);
        ((unsigned int*)out)[(size_t)n * 64 + lane] = pk;
    } else {
        ((float2*)((float*)out + (size_t)n * 128))[lane] = make_float2(a0, a1);
    }
}

extern "C" void kernel_launch(void* const* d_in, const int* in_sizes, int n_in,
                              void* d_out, int out_size, void* d_ws, size_t ws_size,
                              hipStream_t stream) {
    const float* x  = (const float*)d_in[0];
    const int* src  = (const int*)d_in[1];
    const int* dst  = (const int*)d_in[2];
    const float* W1 = (const float*)d_in[3];
    const float* b1 = (const float*)d_in[4];
    const float* W2 = (const float*)d_in[5];
    const float* b2 = (const float*)d_in[6];
    float* out = (float*)d_out;

    const int R = 3;
    int N = in_sizes[0] / 128;
    int E = in_sizes[1] / R;
    int RN = R * N, RE = R * E;
    int NC = (N + CH - 1) / CH;

    size_t h1b = (size_t)N * 128 * 2;          // bf16 hidden
    size_t Tb  = (size_t)R * N * 128 * 2;      // bf16 messages, all relations
    size_t ib  = (size_t)RN * 4;               // one int/float [R][N] array
    size_t bb  = (size_t)RE * 4;               // bucketed src ids
    size_t wb  = (size_t)2 * R * 16384 * 2;    // bf16 transposed weights
    size_t cb  = (size_t)((R * NC * 4 + 255) & ~255);
    if (ws_size < h1b + Tb + 6 * ib + bb + wb + cb) return;

    char* w = (char*)d_ws;
    unsigned short* h1   = (unsigned short*)w;            w += h1b;
    unsigned short* T    = (unsigned short*)w;            w += Tb;
    unsigned int* cntO   = (unsigned int*)w;              w += ib;
    unsigned int* cntI   = (unsigned int*)w;              w += ib;
    float* normO         = (float*)w;                     w += ib;
    float* normI         = (float*)w;                     w += ib;
    int* offs            = (int*)w;                       w += ib;
    int* cursor          = (int*)w;                       w += ib;
    int* bucket          = (int*)w;                       w += bb;
    unsigned short* WbfT = (unsigned short*)w;            w += wb;
    int* csum            = (int*)w;

    hipMemsetAsync(cntO, 0, 2 * ib, stream);   // cntO + cntI contiguous

    wconv_kernel<<<(2 * R * 16384 + 255) / 256, 256, 0, stream>>>(W1, W2, WbfT, 2 * R * 16384);
    deg_kernel<<<(RE + 255) / 256, 256, 0, stream>>>(src, dst, cntO, cntI, RE, E, N);
    norm_kernel<<<(2 * RN + 255) / 256, 256, 0, stream>>>(cntO, cntI, normO, normI, RN);
    scanA<<<R * NC, 256, 0, stream>>>(cntI, csum, N, NC);
    scanB<<<1, 256, 0, stream>>>(csum, R * NC, NC);
    scanC<<<R * NC, 256, 0, stream>>>(cntI, csum, offs, cursor, N, NC);

    int gb = (N + 63) / 64;
    int ngb = (N + 3) / 4;
    int bktb = (RE + 255) / 256;

    // layer-1 gemm co-scheduled with bucket scatter (independent inputs)
    gemm3_bucket<<<gb + bktb, 256, 0, stream>>>(x, WbfT, normO, T, N, gb,
                                                src, dst, cursor, bucket, RE, E, N);
    gather_kernel<true, true><<<ngb, 256, 0, stream>>>(T, bucket, offs, cntI, normI, b1, h1, N, E);

    // layer 2
    gemm3_bf16<<<gb, 256, 0, stream>>>(h1, WbfT + (size_t)3 * 16384, normO, T, N);
    gather_kernel<false, false><<<ngb, 256, 0, stream>>>(T, bucket, offs, cntI, normI, b2, out, N, E);
}